// Round 5
// baseline (509.067 us; speedup 1.0000x reference)
//
#include <hip/hip_runtime.h>
#include <hip/hip_bf16.h>
#include <stdint.h>

#define NBATCH 2
#define NCH    256
#define NTOK   4096
#define NINT   64
#define CHW    64            // column chunk per inner round
#define QCOLS  1024          // columns per quarter-block
#define NCHQ   (QCOLS/CHW)   // 16 rounds per quarter

typedef float  f32x4  __attribute__((ext_vector_type(4)));
typedef __bf16 bf16x8 __attribute__((ext_vector_type(8)));
union U16x8 { uint4 u; bf16x8 b; };
union PK8   { uint4 u; unsigned short s[8]; };

// ---- workspace layout (bytes) ----
// per batch, 10 bf16 arrays of [4096][64]: 0 QS_h 1 QS_l 2 KSF_h 3 KSF_l
// 4 QC_h 5 QC_l 6 KCF_h 7 KCF_l 8 VSF 9 VCF
// Q arrays: row-major [n][64]. K/V arrays: MFMA-FRAGMENT ORDER (see below).
#define SZBF      ((size_t)NTOK*NINT)
// rL (4 bbr x 4096 f32 = 64 KB) overlays VSF of b=0 — dead after k_s1.
#define RL_OFF_B  ((size_t)4194304)

#define OUT_SELF  ((size_t)2097152)
#define OUT_CROSS ((size_t)35651584)
// scratch inside the score_self output region (read by k_epi, then fully
// overwritten by k_s2):
#define FPART_OFF_F (OUT_SELF)                     // [4 bbr][4 qtr][4096][64] f32 = 16 MB
#define LPART_OFF_F (OUT_SELF + (size_t)4194304)   // [4 bbr][4 qtr][4096] f32 = 256 KB

// K fragment layout: element (n, o) ->
//   chunk c = (n>>4)*2 + (o>>5); pos = (((o>>3)&3)*16 + (n&15))*8 + (o&7)
//   KF[c*512 + pos]
// => a wave's (t8,kk) fragment read is KF + ((n0>>4+t8)*2+kk)*512 + lane*8:
//    contiguous 1 KB per instruction.
// V fragment layout: element (o, n) ->
//   chunk c = (n>>6)*8 + ((n>>5)&1)*4 + (o>>4); pos = (((n>>3)&3)*16 + (o&15))*8 + (n&7)
//   VF[c*512 + pos]
// => (kk4,ot) fragment read is VF + ((n0>>6)*8 + kk4*4 + ot)*512 + lane*8.

__device__ inline unsigned short f2bf(float x){
  unsigned int u = __builtin_bit_cast(unsigned int, x);
  u = (u + 0x7FFFu + ((u>>16)&1u)) >> 16;
  return (unsigned short)u;
}
__device__ inline float bf2f(unsigned short s){
  unsigned int u = ((unsigned int)s)<<16;
  return __builtin_bit_cast(float, u);
}

// ---------------- kernel 1: masked projections (fp32) ----------------
__global__ __launch_bounds__(256) void k_proj(
    const float* __restrict__ x, const float* __restrict__ mask,
    const float* __restrict__ wts, const float* __restrict__ wps,
    const float* __restrict__ wgs, const float* __restrict__ wtc,
    const float* __restrict__ wpc, const float* __restrict__ wgc,
    char* __restrict__ ws)
{
  int nt = blockIdx.x;    // 64 n-tiles of 64
  int j  = blockIdx.y;    // which matrix
  int b  = blockIdx.z;
  const float* W; int isBg, mode, arrH, arrL;
  // mode 0 = Q (hi/lo row-major), 1 = V (fragment order), 2 = K (hi/lo fragment order)
  switch (j) {
    case 0: W=wts; isBg=0; mode=2; arrH=2; arrL=3; break; // K_s
    case 1: W=wps; isBg=0; mode=0; arrH=0; arrL=1; break; // Q_s
    case 2: W=wgs; isBg=0; mode=1; arrH=8; arrL=8; break; // V_s
    case 3: W=wpc; isBg=0; mode=0; arrH=4; arrL=5; break; // Q_c
    case 4: W=wtc; isBg=1; mode=2; arrH=6; arrL=7; break; // K_c
    default:W=wgc; isBg=1; mode=1; arrH=9; arrL=9; break; // V_c
  }
  __shared__ float xm[128*64];
  __shared__ float msk[64];
  int t = threadIdx.x;
  if (t < 64) {
    float m = mask[(size_t)b*NTOK + nt*64 + t];
    msk[t] = isBg ? (1.0f - m) : m;
  }
  __syncthreads();
  const float* xb = x + (size_t)b*NCH*NTOK + nt*64;
  int nl = t & 63;
  int o0 = __builtin_amdgcn_readfirstlane((t>>6)*16);
  const float* Wr = W + (size_t)o0*256;
  float acc[16];
  #pragma unroll
  for (int i=0;i<16;i++) acc[i]=0.0f;
  for (int p=0; p<2; ++p){
    const float* xbp = xb + (size_t)p*128*NTOK;
    for (int it = 0; it < 32; ++it) {
      int flat = it*256 + t; int c = flat>>6, n2 = flat&63;
      xm[flat] = xbp[(size_t)c*NTOK + n2] * msk[n2];
    }
    __syncthreads();
    #pragma unroll 4
    for (int cc=0;cc<128;cc++){
      int c = p*128 + cc;
      float xv = xm[cc*64+nl];
      #pragma unroll
      for (int i=0;i<16;i++) acc[i] += Wr[i*256 + c] * xv;
    }
    __syncthreads();
  }
  int n = nt*64 + nl;
  if (mode==0){
    unsigned short* Ah = (unsigned short*)ws + ((size_t)b*10 + arrH)*SZBF;
    unsigned short* Al = (unsigned short*)ws + ((size_t)b*10 + arrL)*SZBF;
    #pragma unroll
    for (int i=0;i<16;i++){
      float v = acc[i];
      unsigned short h = f2bf(v);
      float r = v - bf2f(h);
      Ah[(size_t)n*NINT + o0+i] = h;
      Al[(size_t)n*NINT + o0+i] = f2bf(r);
    }
  } else if (mode==2){
    unsigned short* Ah = (unsigned short*)ws + ((size_t)b*10 + arrH)*SZBF;
    unsigned short* Al = (unsigned short*)ws + ((size_t)b*10 + arrL)*SZBF;
    int kk  = o0>>5;
    int q40 = (o0>>3)&3;
    size_t base = ((size_t)(n>>4)*2 + kk)*512 + (size_t)(q40*16 + (n&15))*8;
    #pragma unroll
    for (int run=0; run<2; ++run){
      PK8 ph, pl;
      #pragma unroll
      for (int i2=0;i2<8;i2++){
        float v = acc[run*8 + i2];
        unsigned short h = f2bf(v);
        ph.s[i2] = h;
        pl.s[i2] = f2bf(v - bf2f(h));
      }
      *(uint4*)(Ah + base + run*128) = ph.u;
      *(uint4*)(Al + base + run*128) = pl.u;
    }
  } else {
    unsigned short* VF = (unsigned short*)ws + ((size_t)b*10 + arrH)*SZBF;
    size_t cBase = (((size_t)nt*8 + ((nl>>5)&1)*4 + (o0>>4)))*512
                 + (size_t)((nl>>3)&3)*128 + (nl&7);
    #pragma unroll
    for (int i=0;i<16;i++) VF[cBase + (size_t)i*8] = f2bf(acc[i]);
  }
}

// ---------------- kernel 2a: sweep 1, barrier-free, fragment loads ----------------
// 512 blocks = 4 bbr x 32 mb2 x 4 qtr; 4 waves; each wave owns TWO 16-row
// m-tiles (halves A/B) and reuses the per-round K/V register fragments for
// both -> halves the duplicated L2 traffic. All K/V loads contiguous
// 1KB/instruction (fragment order). No __syncthreads anywhere; only
// per-wave lP bounce (in-order DS within a wave). FPART/LPART writes are
// nontemporal (streaming scratch; keep K/V resident in L2).
__global__ __launch_bounds__(256,2) void k_s1(char* __restrict__ ws, float* __restrict__ out)
{
  __shared__ __align__(16) unsigned short lP[4][1024];  // 8 KB total

  int blk = blockIdx.x;
  int xcd = blk & 7, idx = blk >> 3;   // idx 0..63
  int bbr = xcd >> 1;                  // 2 XCDs per (b,branch)
  int unit = ((xcd & 1) << 6) | idx;   // 0..127
  int qtr = unit & 3, mb2 = unit >> 2; // mb2 0..31
  int b = bbr >> 1, br = bbr & 1;
  const unsigned short* Qh  = (const unsigned short*)ws + ((size_t)b*10 + (br?4:0))*SZBF;
  const unsigned short* Ql  = Qh + SZBF;
  const unsigned short* KFh = (const unsigned short*)ws + ((size_t)b*10 + (br?6:2))*SZBF;
  const unsigned short* KFl = KFh + SZBF;
  const unsigned short* VF  = (const unsigned short*)ws + ((size_t)b*10 + (br?9:8))*SZBF;

  int t = threadIdx.x, lane = t&63, w = t>>6;
  int rowb = lane&15, q4 = lane>>4, ko = q4*8;
  int mA = mb2*128 + w*16, mB = mA + 64;

  unsigned short* lPw = lP[w];

  U16x8 qhA[2], qlA[2], qhB[2], qlB[2];
  #pragma unroll
  for (int kk=0;kk<2;kk++){
    qhA[kk].u = *(const uint4*)(Qh + (size_t)(mA+rowb)*NINT + kk*32 + ko);
    qlA[kk].u = *(const uint4*)(Ql + (size_t)(mA+rowb)*NINT + kk*32 + ko);
    qhB[kk].u = *(const uint4*)(Qh + (size_t)(mB+rowb)*NINT + kk*32 + ko);
    qlB[kk].u = *(const uint4*)(Ql + (size_t)(mB+rowb)*NINT + kk*32 + ko);
  }

  f32x4 facA[4], facB[4];
  #pragma unroll
  for (int ot=0;ot<4;ot++){ facA[ot]=(f32x4){0,0,0,0}; facB[ot]=(f32x4){0,0,0,0}; }
  float LaccA = 0.0f, LaccB = 0.0f;

  for (int ch=0; ch<NCHQ; ++ch){
    int n0  = qtr*QCOLS + ch*CHW;
    int r16 = n0>>4;
    // ---- load K fragments (regs, reused by both halves) ----
    U16x8 akh[4][2], akl[4][2];
    #pragma unroll
    for (int t8=0; t8<4; ++t8)
      #pragma unroll
      for (int kk=0; kk<2; ++kk){
        size_t cb = ((size_t)(r16 + t8)*2 + kk)*512 + (size_t)lane*8;
        akh[t8][kk].u = *(const uint4*)(KFh + cb);
        akl[t8][kk].u = *(const uint4*)(KFl + cb);
      }
    // ---- load V fragments (regs, reused by both halves) ----
    U16x8 av[2][4];
    #pragma unroll
    for (int kk4=0; kk4<2; ++kk4)
      #pragma unroll
      for (int ot=0; ot<4; ++ot){
        size_t cb = ((size_t)(n0>>6)*8 + kk4*4 + ot)*512 + (size_t)lane*8;
        av[kk4][ot].u = *(const uint4*)(VF + cb);
      }

    #pragma unroll
    for (int hf=0; hf<2; ++hf){
      const U16x8* qh = hf ? qhB : qhA;
      const U16x8* ql = hf ? qlB : qlA;
      f32x4* fac      = hf ? facB : facA;
      float& Lacc     = hf ? LaccB : LaccA;
      // QK^T -> exp -> lP (per-wave)
      #pragma unroll
      for (int t8=0; t8<4; ++t8){
        f32x4 s = {0.0f,0.0f,0.0f,0.0f};
        #pragma unroll
        for (int kk=0; kk<2; ++kk){
          s = __builtin_amdgcn_mfma_f32_16x16x32_bf16(akh[t8][kk].b, qh[kk].b, s, 0,0,0);
          s = __builtin_amdgcn_mfma_f32_16x16x32_bf16(akh[t8][kk].b, ql[kk].b, s, 0,0,0);
          s = __builtin_amdgcn_mfma_f32_16x16x32_bf16(akl[t8][kk].b, qh[kk].b, s, 0,0,0);
        }
        float p0=__expf(s[0]), p1=__expf(s[1]), p2=__expf(s[2]), p3=__expf(s[3]);
        Lacc += (p0+p1)+(p2+p3);
        unsigned int lo = (unsigned int)f2bf(p0) | ((unsigned int)f2bf(p1)<<16);
        unsigned int hi = (unsigned int)f2bf(p2) | ((unsigned int)f2bf(p3)<<16);
        uint2 pk; pk.x = lo; pk.y = hi;
        int g  = t8*2 + (q4>>1);
        int gs = g ^ (rowb&7);
        *(uint2*)(lPw + rowb*64 + gs*8 + (q4&1)*4) = pk;
      }
      // PV from lP + V regs
      #pragma unroll
      for (int kk4=0; kk4<2; ++kk4){
        int rs = (kk4*4 + q4) ^ (rowb&7);
        U16x8 pa;
        pa.u = *(const uint4*)(lPw + rowb*64 + rs*8);
        #pragma unroll
        for (int ot=0; ot<4; ++ot)
          fac[ot] = __builtin_amdgcn_mfma_f32_16x16x32_bf16(pa.b, av[kk4][ot].b, fac[ot], 0,0,0);
      }
    }
  }

  // ---- per-row partial L + unnormalized feat partials, both halves ----
  #pragma unroll
  for (int hf=0; hf<2; ++hf){
    int   m0   = hf ? mB : mA;
    float Lacc = hf ? LaccB : LaccA;
    f32x4* fac = hf ? facB : facA;
    #pragma unroll
    for (int d=16; d<64; d<<=1) Lacc += __shfl_xor(Lacc, d, 64);
    if (q4==0)
      __builtin_nontemporal_store(Lacc,
          out + LPART_OFF_F + (size_t)(bbr*4+qtr)*NTOK + m0 + rowb);
    float* FP = out + FPART_OFF_F + (size_t)(bbr*4+qtr)*NTOK*NINT;
    #pragma unroll
    for (int ot=0; ot<4; ++ot)
      #pragma unroll
      for (int r=0; r<4; ++r)
        __builtin_nontemporal_store(fac[ot][r],
            FP + (size_t)(m0 + q4*4 + r)*NINT + ot*16 + rowb);
  }
}

// ---------------- kernel 3: epilogue + 1/L ----------------
__global__ __launch_bounds__(256) void k_epi(
    const float* __restrict__ x, const float* __restrict__ wout,
    char* __restrict__ ws, float* __restrict__ out)
{
  int nt = blockIdx.x, b = blockIdx.y;   // nt 0..127: 32-row tile
  int t = threadIdx.x;
  const float* FP = out + FPART_OFF_F;
  const float* LP = out + LPART_OFF_F;
  float* rL = (float*)(ws + RL_OFF_B);
  __shared__ float fs[32][65];
  __shared__ float rls[2][32];
  int b0 = b*2, b1 = b*2+1;
  if (t < 64){
    int hb = t>>5, rloc = t&31;
    int bb = b*2 + hb;
    int row = nt*32 + rloc;
    float L = 0.0f;
    #pragma unroll
    for (int q=0;q<4;q++) L += LP[(size_t)(bb*4+q)*NTOK + row];
    float r = 1.0f / L;
    rls[hb][rloc] = r;
    rL[(size_t)bb*NTOK + row] = r;
  }
  __syncthreads();
  for (int it=0; it<8; ++it){
    int flat = it*256 + t; int n_l = flat>>6, o = flat&63;
    int row = nt*32 + n_l;
    float s0=0.0f, s1=0.0f;
    #pragma unroll
    for (int q=0;q<4;q++){
      s0 += __builtin_nontemporal_load(FP + ((size_t)(b0*4+q)*NTOK + row)*NINT + o);
      s1 += __builtin_nontemporal_load(FP + ((size_t)(b1*4+q)*NTOK + row)*NINT + o);
    }
    fs[n_l][o] = s0*rls[0][n_l] + s1*rls[1][n_l];
  }
  __syncthreads();
  int nl = t&31, cg = t>>5, c0 = cg*32;
  float f[64];
  #pragma unroll
  for (int o=0;o<64;o++) f[o] = fs[nl][o];
  const float* wr = wout + (size_t)c0*64;
  int row = nt*32 + nl;
  for (int cc=0; cc<32; ++cc){
    int c = c0 + cc;
    float acc = x[((size_t)b*NCH + c)*NTOK + row];
    #pragma unroll
    for (int o=0;o<64;o++) acc += wr[cc*64+o]*f[o];
    out[((size_t)b*NCH + c)*NTOK + row] = acc;
  }
}

// ---------------- kernel 4: sweep 2, barrier-free score write ----------------
// 512 blocks = 4 bbr x 32 mb2 x 4 qtr; each wave owns TWO 16-row m-tiles
// and reuses every K register fragment for both -> K L2 traffic halves
// (1.05 GB -> 0.52 GB). K fragments loaded per-t8 (short live range, no
// VGPR blowup). No LDS, no barriers; nt stores fire-and-forget.
__global__ __launch_bounds__(256,2) void k_s2(const char* __restrict__ ws, float* __restrict__ out)
{
  int blk = blockIdx.x;
  int xcd = blk & 7, idx = blk >> 3;   // idx 0..63
  int bbr = xcd >> 1;
  int unit = ((xcd & 1) << 6) | idx;   // 0..127
  int qtr = unit & 3, mb2 = unit >> 2; // 0..31
  int b = bbr >> 1, br = bbr & 1;
  const unsigned short* Qh  = (const unsigned short*)ws + ((size_t)b*10 + (br?4:0))*SZBF;
  const unsigned short* Ql  = Qh + SZBF;
  const unsigned short* KFh = (const unsigned short*)ws + ((size_t)b*10 + (br?6:2))*SZBF;
  const unsigned short* KFl = KFh + SZBF;

  int t = threadIdx.x, lane = t&63, w = t>>6;
  int rowb = lane&15, q4 = lane>>4, ko = q4*8;
  int mA = mb2*128 + w*16, mB = mA + 64;
  int mrowA = mA + rowb,   mrowB = mB + rowb;

  const float* rL = (const float*)(ws + RL_OFF_B) + (size_t)bbr*NTOK;
  float rLpA = rL[mrowA], rLpB = rL[mrowB];

  U16x8 qhA[2], qlA[2], qhB[2], qlB[2];
  #pragma unroll
  for (int kk=0;kk<2;kk++){
    qhA[kk].u = *(const uint4*)(Qh + (size_t)mrowA*NINT + kk*32 + ko);
    qlA[kk].u = *(const uint4*)(Ql + (size_t)mrowA*NINT + kk*32 + ko);
    qhB[kk].u = *(const uint4*)(Qh + (size_t)mrowB*NINT + kk*32 + ko);
    qlB[kk].u = *(const uint4*)(Ql + (size_t)mrowB*NINT + kk*32 + ko);
  }

  float* outS = out + (br ? OUT_CROSS : OUT_SELF) + (size_t)b*NTOK*NTOK;
  float* outA = outS + (size_t)mrowA*NTOK;
  float* outB = outS + (size_t)mrowB*NTOK;

  for (int ch=0; ch<NCHQ; ++ch){
    int n0  = qtr*QCOLS + ch*CHW;
    int r16 = n0>>4;
    #pragma unroll
    for (int t8=0; t8<4; ++t8){
      U16x8 ah[2], al[2];
      #pragma unroll
      for (int kk=0; kk<2; ++kk){
        size_t cb = ((size_t)(r16 + t8)*2 + kk)*512 + (size_t)lane*8;
        ah[kk].u = *(const uint4*)(KFh + cb);
        al[kk].u = *(const uint4*)(KFl + cb);
      }
      f32x4 sA = {0.0f,0.0f,0.0f,0.0f}, sB = {0.0f,0.0f,0.0f,0.0f};
      #pragma unroll
      for (int kk=0; kk<2; ++kk){
        sA = __builtin_amdgcn_mfma_f32_16x16x32_bf16(ah[kk].b, qhA[kk].b, sA, 0,0,0);
        sA = __builtin_amdgcn_mfma_f32_16x16x32_bf16(ah[kk].b, qlA[kk].b, sA, 0,0,0);
        sA = __builtin_amdgcn_mfma_f32_16x16x32_bf16(al[kk].b, qhA[kk].b, sA, 0,0,0);
        sB = __builtin_amdgcn_mfma_f32_16x16x32_bf16(ah[kk].b, qhB[kk].b, sB, 0,0,0);
        sB = __builtin_amdgcn_mfma_f32_16x16x32_bf16(ah[kk].b, qlB[kk].b, sB, 0,0,0);
        sB = __builtin_amdgcn_mfma_f32_16x16x32_bf16(al[kk].b, qhB[kk].b, sB, 0,0,0);
      }
      f32x4 pA, pB;
      pA[0] = __expf(sA[0])*rLpA; pA[1] = __expf(sA[1])*rLpA;
      pA[2] = __expf(sA[2])*rLpA; pA[3] = __expf(sA[3])*rLpA;
      pB[0] = __expf(sB[0])*rLpB; pB[1] = __expf(sB[1])*rLpB;
      pB[2] = __expf(sB[2])*rLpB; pB[3] = __expf(sB[3])*rLpB;
      int coff = n0 + t8*16 + q4*4;
      __builtin_nontemporal_store(pA, (f32x4*)(outA + coff));
      __builtin_nontemporal_store(pB, (f32x4*)(outB + coff));
    }
  }
}

extern "C" void kernel_launch(void* const* d_in, const int* in_sizes, int n_in,
                              void* d_out, int out_size, void* d_ws, size_t ws_size,
                              hipStream_t stream)
{
  const float* x    = (const float*)d_in[0];
  const float* mask = (const float*)d_in[1];
  const float* wts  = (const float*)d_in[2];
  const float* wps  = (const float*)d_in[3];
  const float* wgs  = (const float*)d_in[4];
  const float* wtc  = (const float*)d_in[5];
  const float* wpc  = (const float*)d_in[6];
  const float* wgc  = (const float*)d_in[7];
  const float* wout = (const float*)d_in[8];
  float* out = (float*)d_out;
  char*  ws  = (char*)d_ws;
  (void)in_sizes; (void)n_in; (void)out_size; (void)ws_size;

  k_proj <<<dim3(64,6,NBATCH), 256, 0, stream>>>(x, mask, wts, wps, wgs, wtc, wpc, wgc, ws);
  k_s1   <<<dim3(512), 256, 0, stream>>>(ws, out);
  k_epi  <<<dim3(128,NBATCH), 256, 0, stream>>>(x, wout, ws, out);  // before k_s2 (reads FPART)
  k_s2   <<<dim3(512), 256, 0, stream>>>(ws, out);
}

// Round 6
// 485.217 us; speedup vs baseline: 1.0492x; 1.0492x over previous
//
#include <hip/hip_runtime.h>
#include <hip/hip_bf16.h>
#include <stdint.h>

#define NBATCH 2
#define NCH    256
#define NTOK   4096
#define NINT   64
#define CHW    64            // column chunk per inner round
#define QCOLS  1024          // columns per quarter-block
#define NCHQ   (QCOLS/CHW)   // 16 rounds per quarter

typedef float  f32x4  __attribute__((ext_vector_type(4)));
typedef __bf16 bf16x8 __attribute__((ext_vector_type(8)));
union U16x8 { uint4 u; bf16x8 b; };
union PK8   { uint4 u; unsigned short s[8]; };

// ---- workspace layout (bytes) ----
// per batch, 10 bf16 arrays of [4096][64]: 0 QS_h 1 QS_l 2 KSF_h 3 KSF_l
// 4 QC_h 5 QC_l 6 KCF_h 7 KCF_l 8 VSF 9 VCF
// Q arrays: row-major [n][64]. K/V arrays: MFMA-FRAGMENT ORDER (see below).
#define SZBF      ((size_t)NTOK*NINT)
// rL (4 bbr x 4096 f32 = 64 KB) overlays VSF of b=0 — dead after k_s1.
#define RL_OFF_B  ((size_t)4194304)

#define OUT_SELF  ((size_t)2097152)
#define OUT_CROSS ((size_t)35651584)
// scratch inside the score_self output region (read by k_epi, then fully
// overwritten by k_s2):
#define FPART_OFF_F (OUT_SELF)                     // [4 bbr][4 qtr][4096][64] f32 = 16 MB
#define LPART_OFF_F (OUT_SELF + (size_t)4194304)   // [4 bbr][4 qtr][4096] f32 = 256 KB

// K fragment layout: element (n, o) ->
//   chunk c = (n>>4)*2 + (o>>5); pos = (((o>>3)&3)*16 + (n&15))*8 + (o&7)
//   KF[c*512 + pos]
// => a wave's (t8,kk) fragment read is KF + ((n0>>4+t8)*2+kk)*512 + lane*8:
//    contiguous 1 KB per instruction.
// V fragment layout: element (o, n) ->
//   chunk c = (n>>6)*8 + ((n>>5)&1)*4 + (o>>4); pos = (((n>>3)&3)*16 + (o&15))*8 + (n&7)
//   VF[c*512 + pos]
// => (kk4,ot) fragment read is VF + ((n0>>6)*8 + kk4*4 + ot)*512 + lane*8.

__device__ inline unsigned short f2bf(float x){
  unsigned int u = __builtin_bit_cast(unsigned int, x);
  u = (u + 0x7FFFu + ((u>>16)&1u)) >> 16;
  return (unsigned short)u;
}
__device__ inline float bf2f(unsigned short s){
  unsigned int u = ((unsigned int)s)<<16;
  return __builtin_bit_cast(float, u);
}

// ---------------- kernel 1: masked projections (fp32) ----------------
__global__ __launch_bounds__(256) void k_proj(
    const float* __restrict__ x, const float* __restrict__ mask,
    const float* __restrict__ wts, const float* __restrict__ wps,
    const float* __restrict__ wgs, const float* __restrict__ wtc,
    const float* __restrict__ wpc, const float* __restrict__ wgc,
    char* __restrict__ ws)
{
  int nt = blockIdx.x;    // 64 n-tiles of 64
  int j  = blockIdx.y;    // which matrix
  int b  = blockIdx.z;
  const float* W; int isBg, mode, arrH, arrL;
  // mode 0 = Q (hi/lo row-major), 1 = V (fragment order), 2 = K (hi/lo fragment order)
  switch (j) {
    case 0: W=wts; isBg=0; mode=2; arrH=2; arrL=3; break; // K_s
    case 1: W=wps; isBg=0; mode=0; arrH=0; arrL=1; break; // Q_s
    case 2: W=wgs; isBg=0; mode=1; arrH=8; arrL=8; break; // V_s
    case 3: W=wpc; isBg=0; mode=0; arrH=4; arrL=5; break; // Q_c
    case 4: W=wtc; isBg=1; mode=2; arrH=6; arrL=7; break; // K_c
    default:W=wgc; isBg=1; mode=1; arrH=9; arrL=9; break; // V_c
  }
  __shared__ float xm[128*64];
  __shared__ float msk[64];
  int t = threadIdx.x;
  if (t < 64) {
    float m = mask[(size_t)b*NTOK + nt*64 + t];
    msk[t] = isBg ? (1.0f - m) : m;
  }
  __syncthreads();
  const float* xb = x + (size_t)b*NCH*NTOK + nt*64;
  int nl = t & 63;
  int o0 = __builtin_amdgcn_readfirstlane((t>>6)*16);
  const float* Wr = W + (size_t)o0*256;
  float acc[16];
  #pragma unroll
  for (int i=0;i<16;i++) acc[i]=0.0f;
  for (int p=0; p<2; ++p){
    const float* xbp = xb + (size_t)p*128*NTOK;
    for (int it = 0; it < 32; ++it) {
      int flat = it*256 + t; int c = flat>>6, n2 = flat&63;
      xm[flat] = xbp[(size_t)c*NTOK + n2] * msk[n2];
    }
    __syncthreads();
    #pragma unroll 4
    for (int cc=0;cc<128;cc++){
      int c = p*128 + cc;
      float xv = xm[cc*64+nl];
      #pragma unroll
      for (int i=0;i<16;i++) acc[i] += Wr[i*256 + c] * xv;
    }
    __syncthreads();
  }
  int n = nt*64 + nl;
  if (mode==0){
    unsigned short* Ah = (unsigned short*)ws + ((size_t)b*10 + arrH)*SZBF;
    unsigned short* Al = (unsigned short*)ws + ((size_t)b*10 + arrL)*SZBF;
    #pragma unroll
    for (int i=0;i<16;i++){
      float v = acc[i];
      unsigned short h = f2bf(v);
      float r = v - bf2f(h);
      Ah[(size_t)n*NINT + o0+i] = h;
      Al[(size_t)n*NINT + o0+i] = f2bf(r);
    }
  } else if (mode==2){
    unsigned short* Ah = (unsigned short*)ws + ((size_t)b*10 + arrH)*SZBF;
    unsigned short* Al = (unsigned short*)ws + ((size_t)b*10 + arrL)*SZBF;
    int kk  = o0>>5;
    int q40 = (o0>>3)&3;
    size_t base = ((size_t)(n>>4)*2 + kk)*512 + (size_t)(q40*16 + (n&15))*8;
    #pragma unroll
    for (int run=0; run<2; ++run){
      PK8 ph, pl;
      #pragma unroll
      for (int i2=0;i2<8;i2++){
        float v = acc[run*8 + i2];
        unsigned short h = f2bf(v);
        ph.s[i2] = h;
        pl.s[i2] = f2bf(v - bf2f(h));
      }
      *(uint4*)(Ah + base + run*128) = ph.u;
      *(uint4*)(Al + base + run*128) = pl.u;
    }
  } else {
    unsigned short* VF = (unsigned short*)ws + ((size_t)b*10 + arrH)*SZBF;
    size_t cBase = (((size_t)nt*8 + ((nl>>5)&1)*4 + (o0>>4)))*512
                 + (size_t)((nl>>3)&3)*128 + (nl&7);
    #pragma unroll
    for (int i=0;i<16;i++) VF[cBase + (size_t)i*8] = f2bf(acc[i]);
  }
}

// ---------------- kernel 2a: sweep 1, barrier-free, fragment loads ----------------
// 512 blocks = 4 bbr x 32 mb2 x 4 qtr; 4 waves; each wave owns TWO 16-row
// m-tiles (halves A/B) and reuses the per-round K/V register fragments for
// both -> halves the duplicated L2 traffic. All K/V loads contiguous
// 1KB/instruction (fragment order). No __syncthreads anywhere; only
// per-wave lP bounce (in-order DS within a wave).
__global__ __launch_bounds__(256,2) void k_s1(char* __restrict__ ws, float* __restrict__ out)
{
  __shared__ __align__(16) unsigned short lP[4][1024];  // 8 KB total

  int blk = blockIdx.x;
  int xcd = blk & 7, idx = blk >> 3;   // idx 0..63
  int bbr = xcd >> 1;                  // 2 XCDs per (b,branch)
  int unit = ((xcd & 1) << 6) | idx;   // 0..127
  int qtr = unit & 3, mb2 = unit >> 2; // mb2 0..31
  int b = bbr >> 1, br = bbr & 1;
  const unsigned short* Qh  = (const unsigned short*)ws + ((size_t)b*10 + (br?4:0))*SZBF;
  const unsigned short* Ql  = Qh + SZBF;
  const unsigned short* KFh = (const unsigned short*)ws + ((size_t)b*10 + (br?6:2))*SZBF;
  const unsigned short* KFl = KFh + SZBF;
  const unsigned short* VF  = (const unsigned short*)ws + ((size_t)b*10 + (br?9:8))*SZBF;

  int t = threadIdx.x, lane = t&63, w = t>>6;
  int rowb = lane&15, q4 = lane>>4, ko = q4*8;
  int mA = mb2*128 + w*16, mB = mA + 64;

  unsigned short* lPw = lP[w];

  U16x8 qhA[2], qlA[2], qhB[2], qlB[2];
  #pragma unroll
  for (int kk=0;kk<2;kk++){
    qhA[kk].u = *(const uint4*)(Qh + (size_t)(mA+rowb)*NINT + kk*32 + ko);
    qlA[kk].u = *(const uint4*)(Ql + (size_t)(mA+rowb)*NINT + kk*32 + ko);
    qhB[kk].u = *(const uint4*)(Qh + (size_t)(mB+rowb)*NINT + kk*32 + ko);
    qlB[kk].u = *(const uint4*)(Ql + (size_t)(mB+rowb)*NINT + kk*32 + ko);
  }

  f32x4 facA[4], facB[4];
  #pragma unroll
  for (int ot=0;ot<4;ot++){ facA[ot]=(f32x4){0,0,0,0}; facB[ot]=(f32x4){0,0,0,0}; }
  float LaccA = 0.0f, LaccB = 0.0f;

  for (int ch=0; ch<NCHQ; ++ch){
    int n0  = qtr*QCOLS + ch*CHW;
    int r16 = n0>>4;
    // ---- load K fragments (regs, reused by both halves) ----
    U16x8 akh[4][2], akl[4][2];
    #pragma unroll
    for (int t8=0; t8<4; ++t8)
      #pragma unroll
      for (int kk=0; kk<2; ++kk){
        size_t cb = ((size_t)(r16 + t8)*2 + kk)*512 + (size_t)lane*8;
        akh[t8][kk].u = *(const uint4*)(KFh + cb);
        akl[t8][kk].u = *(const uint4*)(KFl + cb);
      }
    // ---- load V fragments (regs, reused by both halves) ----
    U16x8 av[2][4];
    #pragma unroll
    for (int kk4=0; kk4<2; ++kk4)
      #pragma unroll
      for (int ot=0; ot<4; ++ot){
        size_t cb = ((size_t)(n0>>6)*8 + kk4*4 + ot)*512 + (size_t)lane*8;
        av[kk4][ot].u = *(const uint4*)(VF + cb);
      }

    #pragma unroll
    for (int hf=0; hf<2; ++hf){
      const U16x8* qh = hf ? qhB : qhA;
      const U16x8* ql = hf ? qlB : qlA;
      f32x4* fac      = hf ? facB : facA;
      float& Lacc     = hf ? LaccB : LaccA;
      // QK^T -> exp -> lP (per-wave)
      #pragma unroll
      for (int t8=0; t8<4; ++t8){
        f32x4 s = {0.0f,0.0f,0.0f,0.0f};
        #pragma unroll
        for (int kk=0; kk<2; ++kk){
          s = __builtin_amdgcn_mfma_f32_16x16x32_bf16(akh[t8][kk].b, qh[kk].b, s, 0,0,0);
          s = __builtin_amdgcn_mfma_f32_16x16x32_bf16(akh[t8][kk].b, ql[kk].b, s, 0,0,0);
          s = __builtin_amdgcn_mfma_f32_16x16x32_bf16(akl[t8][kk].b, qh[kk].b, s, 0,0,0);
        }
        float p0=__expf(s[0]), p1=__expf(s[1]), p2=__expf(s[2]), p3=__expf(s[3]);
        Lacc += (p0+p1)+(p2+p3);
        unsigned int lo = (unsigned int)f2bf(p0) | ((unsigned int)f2bf(p1)<<16);
        unsigned int hi = (unsigned int)f2bf(p2) | ((unsigned int)f2bf(p3)<<16);
        uint2 pk; pk.x = lo; pk.y = hi;
        int g  = t8*2 + (q4>>1);
        int gs = g ^ (rowb&7);
        *(uint2*)(lPw + rowb*64 + gs*8 + (q4&1)*4) = pk;
      }
      // PV from lP + V regs
      #pragma unroll
      for (int kk4=0; kk4<2; ++kk4){
        int rs = (kk4*4 + q4) ^ (rowb&7);
        U16x8 pa;
        pa.u = *(const uint4*)(lPw + rowb*64 + rs*8);
        #pragma unroll
        for (int ot=0; ot<4; ++ot)
          fac[ot] = __builtin_amdgcn_mfma_f32_16x16x32_bf16(pa.b, av[kk4][ot].b, fac[ot], 0,0,0);
      }
    }
  }

  // ---- per-row partial L + unnormalized feat partials, both halves ----
  #pragma unroll
  for (int hf=0; hf<2; ++hf){
    int   m0   = hf ? mB : mA;
    float Lacc = hf ? LaccB : LaccA;
    f32x4* fac = hf ? facB : facA;
    #pragma unroll
    for (int d=16; d<64; d<<=1) Lacc += __shfl_xor(Lacc, d, 64);
    if (q4==0)
      out[LPART_OFF_F + (size_t)(bbr*4+qtr)*NTOK + m0 + rowb] = Lacc;
    float* FP = out + FPART_OFF_F + (size_t)(bbr*4+qtr)*NTOK*NINT;
    #pragma unroll
    for (int ot=0; ot<4; ++ot)
      #pragma unroll
      for (int r=0; r<4; ++r)
        FP[(size_t)(m0 + q4*4 + r)*NINT + ot*16 + rowb] = fac[ot][r];
  }
}

// ---------------- kernel 3: epilogue + 1/L ----------------
__global__ __launch_bounds__(256) void k_epi(
    const float* __restrict__ x, const float* __restrict__ wout,
    char* __restrict__ ws, float* __restrict__ out)
{
  int nt = blockIdx.x, b = blockIdx.y;   // nt 0..127: 32-row tile
  int t = threadIdx.x;
  const float* FP = out + FPART_OFF_F;
  const float* LP = out + LPART_OFF_F;
  float* rL = (float*)(ws + RL_OFF_B);
  __shared__ float fs[32][65];
  __shared__ float rls[2][32];
  int b0 = b*2, b1 = b*2+1;
  if (t < 64){
    int hb = t>>5, rloc = t&31;
    int bb = b*2 + hb;
    int row = nt*32 + rloc;
    float L = 0.0f;
    #pragma unroll
    for (int q=0;q<4;q++) L += LP[(size_t)(bb*4+q)*NTOK + row];
    float r = 1.0f / L;
    rls[hb][rloc] = r;
    rL[(size_t)bb*NTOK + row] = r;
  }
  __syncthreads();
  for (int it=0; it<8; ++it){
    int flat = it*256 + t; int n_l = flat>>6, o = flat&63;
    int row = nt*32 + n_l;
    float s0=0.0f, s1=0.0f;
    #pragma unroll
    for (int q=0;q<4;q++){
      s0 += FP[((size_t)(b0*4+q)*NTOK + row)*NINT + o];
      s1 += FP[((size_t)(b1*4+q)*NTOK + row)*NINT + o];
    }
    fs[n_l][o] = s0*rls[0][n_l] + s1*rls[1][n_l];
  }
  __syncthreads();
  int nl = t&31, cg = t>>5, c0 = cg*32;
  float f[64];
  #pragma unroll
  for (int o=0;o<64;o++) f[o] = fs[nl][o];
  const float* wr = wout + (size_t)c0*64;
  int row = nt*32 + nl;
  for (int cc=0; cc<32; ++cc){
    int c = c0 + cc;
    float acc = x[((size_t)b*NCH + c)*NTOK + row];
    #pragma unroll
    for (int o=0;o<64;o++) acc += wr[cc*64+o]*f[o];
    out[((size_t)b*NCH + c)*NTOK + row] = acc;
  }
}

// ---------------- kernel 4: sweep 2, barrier-free score write ----------------
// 1024 blocks = 4 bbr x 64 mb x 4 qtr; (256,4) -> 4 blocks/CU = 16 waves/CU
// (store-queue depth is what covers HBM write latency). No LDS, no barriers;
// K fragments contiguous from L2; nt stores fire-and-forget.
__global__ __launch_bounds__(256,4) void k_s2(const char* __restrict__ ws, float* __restrict__ out)
{
  int blk = blockIdx.x;
  int xcd = blk & 7, idx = blk >> 3;
  int bbr = xcd >> 1;
  int unit = ((xcd & 1) << 7) | idx;
  int qtr = unit & 3, mb = unit >> 2;
  int b = bbr >> 1, br = bbr & 1;
  const unsigned short* Qh  = (const unsigned short*)ws + ((size_t)b*10 + (br?4:0))*SZBF;
  const unsigned short* Ql  = Qh + SZBF;
  const unsigned short* KFh = (const unsigned short*)ws + ((size_t)b*10 + (br?6:2))*SZBF;
  const unsigned short* KFl = KFh + SZBF;

  int t = threadIdx.x, lane = t&63, w = t>>6;
  int rowb = lane&15, q4 = lane>>4, ko = q4*8;
  int m0 = mb*64 + w*16, mrow = m0 + rowb;

  float rLp = ((const float*)(ws + RL_OFF_B))[(size_t)bbr*NTOK + mrow];

  U16x8 qh[2], ql[2];
  #pragma unroll
  for (int kk=0;kk<2;kk++){
    qh[kk].u = *(const uint4*)(Qh + (size_t)mrow*NINT + kk*32 + ko);
    ql[kk].u = *(const uint4*)(Ql + (size_t)mrow*NINT + kk*32 + ko);
  }

  float* outS = out + (br ? OUT_CROSS : OUT_SELF) + (size_t)b*NTOK*NTOK;

  for (int ch=0; ch<NCHQ; ++ch){
    int n0  = qtr*QCOLS + ch*CHW;
    int r16 = n0>>4;
    #pragma unroll
    for (int t8=0; t8<4; ++t8){
      f32x4 s = {0.0f,0.0f,0.0f,0.0f};
      #pragma unroll
      for (int kk=0; kk<2; ++kk){
        size_t cb = ((size_t)(r16 + t8)*2 + kk)*512 + (size_t)lane*8;
        U16x8 ah, al;
        ah.u = *(const uint4*)(KFh + cb);
        al.u = *(const uint4*)(KFl + cb);
        s = __builtin_amdgcn_mfma_f32_16x16x32_bf16(ah.b, qh[kk].b, s, 0,0,0);
        s = __builtin_amdgcn_mfma_f32_16x16x32_bf16(ah.b, ql[kk].b, s, 0,0,0);
        s = __builtin_amdgcn_mfma_f32_16x16x32_bf16(al.b, qh[kk].b, s, 0,0,0);
      }
      f32x4 p;
      p[0] = __expf(s[0])*rLp; p[1] = __expf(s[1])*rLp;
      p[2] = __expf(s[2])*rLp; p[3] = __expf(s[3])*rLp;
      __builtin_nontemporal_store(p,
          (f32x4*)(outS + (size_t)mrow*NTOK + n0 + t8*16 + q4*4));
    }
  }
}

extern "C" void kernel_launch(void* const* d_in, const int* in_sizes, int n_in,
                              void* d_out, int out_size, void* d_ws, size_t ws_size,
                              hipStream_t stream)
{
  const float* x    = (const float*)d_in[0];
  const float* mask = (const float*)d_in[1];
  const float* wts  = (const float*)d_in[2];
  const float* wps  = (const float*)d_in[3];
  const float* wgs  = (const float*)d_in[4];
  const float* wtc  = (const float*)d_in[5];
  const float* wpc  = (const float*)d_in[6];
  const float* wgc  = (const float*)d_in[7];
  const float* wout = (const float*)d_in[8];
  float* out = (float*)d_out;
  char*  ws  = (char*)d_ws;
  (void)in_sizes; (void)n_in; (void)out_size; (void)ws_size;

  k_proj <<<dim3(64,6,NBATCH), 256, 0, stream>>>(x, mask, wts, wps, wgs, wtc, wpc, wgc, ws);
  k_s1   <<<dim3(512), 256, 0, stream>>>(ws, out);
  k_epi  <<<dim3(128,NBATCH), 256, 0, stream>>>(x, wout, ws, out);  // before k_s2 (reads FPART)
  k_s2   <<<dim3(1024), 256, 0, stream>>>(ws, out);
}